// Round 4
// baseline (8414.098 us; speedup 1.0000x reference)
//
#include <hip/hip_runtime.h>
#include <math.h>

#define B_   32
#define S_   1024
#define DIN  512
#define DH   512
#define KTOT 1024          // DH (Wh part) + DIN (Wx part) in Bws
#define NWG  64
#define TPB  256
#define HSCAP 1024         // bounded handshake rounds (~0.3 ms worst case)

typedef short short8 __attribute__((ext_vector_type(8)));  // 8 bf16 (4 VGPRs)
typedef float f32x4  __attribute__((ext_vector_type(4)));
typedef unsigned long long u64;

#define SENT  0xFFFFFFFFFFFFFFFFULL  // 4x bf16 NaN; |H|<1 so never produced by f2bf
#define TESTV 0xFFFFFFFFFFFFFFFEULL  // handshake probe value (!= SENT, != poison)

__device__ __forceinline__ unsigned short f2bf(float f) {
  unsigned u = __float_as_uint(f);
  u += 0x7FFFu + ((u >> 16) & 1u);   // RNE
  return (unsigned short)(u >> 16);
}
__device__ __forceinline__ float sigmoid_f(float z) {
  return 1.f / (1.f + __expf(-z));
}
__device__ __forceinline__ float tanh_f(float z) {
  float e = __expf(-2.f * fabsf(z));
  float t = (1.f - e) / (1.f + e);
  return z < 0.f ? -t : t;
}
__device__ __forceinline__ f32x4 mfma16(short8 a, short8 b, f32x4 c) {
  return __builtin_amdgcn_mfma_f32_16x16x32_bf16(a, b, c, 0, 0, 0);
}
// proven LLC transport (rounds 0-1)
__device__ __forceinline__ u64 cload(const u64* p) {
  return __hip_atomic_load(p, __ATOMIC_RELAXED, __HIP_MEMORY_SCOPE_AGENT);
}
__device__ __forceinline__ void cstore(u64* p, u64 v) {
  __hip_atomic_store(p, v, __ATOMIC_RELAXED, __HIP_MEMORY_SCOPE_AGENT);
}
// XCD-local transport: plain (write-through to local L2) store; L1-bypass load
__device__ __forceinline__ void fstore(u64* p, u64 v) {
  *(volatile u64*)p = v;
}
__device__ __forceinline__ u64 fload(const u64* p) {
  u64 v;
  asm volatile("global_load_dwordx2 %0, %1, off sc0" : "=v"(v) : "v"(p) : "memory");
  return v;   // NOT valid until s_waitcnt; callers drain + sched_barrier before use
}

// B-operand layout: Bws[idx 0..31][c 0..63][k 0..1023], c = gate*16 + jj,
// hcol = idx*16 + jj, k<512 -> Wh, else Wx.
__global__ void k_prep(const float* __restrict__ Whi, const float* __restrict__ Whf,
                       const float* __restrict__ Who, const float* __restrict__ Whc,
                       const float* __restrict__ Wxi, const float* __restrict__ Wxf,
                       const float* __restrict__ Wxo, const float* __restrict__ Wxc,
                       unsigned short* __restrict__ Bws, u64* __restrict__ hfast,
                       unsigned* __restrict__ bar) {
  int chunk = blockIdx.x * TPB + threadIdx.x;      // 0..262143, 8 elems each
  int idx = chunk >> 13;
  int rem = chunk & 8191;
  int c   = rem >> 7;             // gate*16 + jj
  int k8  = (rem & 127) << 3;
  int g    = c >> 4;
  int hcol = (idx << 4) | (c & 15);
  const float* Wh = (g == 0) ? Whi : (g == 1) ? Whf : (g == 2) ? Who : Whc;
  const float* Wx = (g == 0) ? Wxi : (g == 1) ? Wxf : (g == 2) ? Wxo : Wxc;
  short8 sv;
  #pragma unroll
  for (int j = 0; j < 8; ++j) {
    int k = k8 + j;
    float f = (k < DH) ? Wh[(size_t)k * DH + hcol] : Wx[(size_t)(k - DH) * DH + hcol];
    sv[j] = (short)f2bf(f);
  }
  *(short8*)(Bws + (size_t)chunk * 8) = sv;
  if (blockIdx.x == 0) {
    // zero barrier region (done | ok | bar2 | spare = 1024 u32)
    #pragma unroll
    for (int r = 0; r < 4; ++r) bar[threadIdx.x + r * 256] = 0;
    // erase all groups' buf0 (handshake buffer) at LLC so stale TESTV from a
    // previous launch can never produce a false handshake pass
    #pragma unroll
    for (int j = 0; j < 16; ++j) {
      int u = threadIdx.x * 16 + j;            // 0..4095
      cstore(&hfast[(size_t)(u >> 9) * 2048 + (u & 511)], SENT);
    }
  }
}

// Persistent LSTM scan. 8 groups x 8 WGs x 4 batches; group gid = w&7 (co-XCD
// under round-robin dispatch, VERIFIED at runtime by a bounded handshake over
// the fast transport with consensus over proven agent atomics; any anomaly ->
// fallback to the proven LLC protocol in a disjoint region).
// Waves are autonomous: 16 hcols x 4 gates, full-K Wh resident (256 VGPR),
// H exchange lands directly in MFMA A-fragments, zero in-loop barriers.
// x-projections computed in-scan every 8 steps (MFMA, streamed Wx, f32 kept).
__launch_bounds__(TPB, 1)
__global__ void k_scan(const float* __restrict__ x,
                       const float* __restrict__ bi, const float* __restrict__ bfv,
                       const float* __restrict__ bo, const float* __restrict__ bc,
                       const unsigned short* __restrict__ Bws,
                       u64* __restrict__ hfast,    // 8 groups x 4 bufs x 512 u64
                       u64* __restrict__ hfb,      // fallback region, same shape
                       unsigned* __restrict__ bar, // done[8x32] | ok | bar2
                       float* __restrict__ out) {
  __shared__ int sh_bad;
  __shared__ int sh_fast;

  const int tid  = threadIdx.x;
  const int w    = blockIdx.x;
  const int lane = tid & 63;
  const int wv   = tid >> 6;
  const int l15  = lane & 15;
  const int kq8  = (lane >> 4) << 3;
  const int b4   = lane & 3;

  const int gid = w & 7;            // presumptive XCD (round-robin)
  const int mem = w >> 3;           // position within group -> hcol slice
  const int hbase = mem * 64 + wv * 16;
  const int idx   = mem * 4 + wv;   // Bws idx block for this wave's 16 hcols
  const int hcol  = hbase + l15;
  const int pslot = (hbase + (l15 & ~3)) | b4;   // own publish/sentinel slot
  const int B0    = gid * 4;        // first batch of this group

  const float pbi = bi[hcol], pbf = bfv[hcol], pbo = bo[hcol], pbc = bc[hcol];

  // ---- weights resident: full-K Wh fragments for 16 hcols x 4 gates ----
  short8 bfrag[16][4];
  #pragma unroll
  for (int ks = 0; ks < 16; ++ks)
    #pragma unroll
    for (int g = 0; g < 4; ++g)
      bfrag[ks][g] = *(const short8*)(Bws +
          ((size_t)(idx * 64 + g * 16 + l15) * KTOT + ks * 32 + kq8));

  // ================= transport handshake (bounded, consensus) =================
  u64* fs = hfast + (size_t)gid * 2048;      // group's fast region (buf0 = [0,512))
  if (lane < 16) fstore(fs + pslot, TESTV);
  __builtin_amdgcn_s_waitcnt(0);

  int miss0 = 1, miss1 = 1;                  // poll slots tid and tid+256
  for (int r = 0; r < HSCAP && (miss0 | miss1); ++r) {
    u64 a = 0, c = 0;
    if (miss0) a = fload(fs + tid);
    if (miss1) c = fload(fs + tid + 256);
    __builtin_amdgcn_s_waitcnt(0);
    __builtin_amdgcn_sched_barrier(0);
    if (miss0 && a == TESTV) miss0 = 0;
    if (miss1 && c == TESTV) miss1 = 0;
  }
  if (tid == 0) sh_bad = 0;
  __syncthreads();
  if (miss0 | miss1) atomicAdd(&sh_bad, 1);
  __syncthreads();
  const int myok = (sh_bad == 0);

  if (tid == 0) {
    if (myok)
      __hip_atomic_fetch_add(&bar[256 + gid * 32], 1u,
                             __ATOMIC_RELAXED, __HIP_MEMORY_SCOPE_AGENT);
    __builtin_amdgcn_s_waitcnt(0);           // ok-add committed before done-add
    __hip_atomic_fetch_add(&bar[gid * 32], 1u,
                           __ATOMIC_RELAXED, __HIP_MEMORY_SCOPE_AGENT);
    for (;;) {
      if (__hip_atomic_load(&bar[gid * 32],
                            __ATOMIC_RELAXED, __HIP_MEMORY_SCOPE_AGENT) >= 8u) break;
      __builtin_amdgcn_s_sleep(1);
    }
    sh_fast = (__hip_atomic_load(&bar[256 + gid * 32],
                                 __ATOMIC_RELAXED, __HIP_MEMORY_SCOPE_AGENT) == 8u);
  }
  __syncthreads();
  const int fast = sh_fast;
  u64* gbuf = (fast ? hfast : hfb) + (size_t)gid * 2048;

  // ---- pre-sentinel buf0,buf1 via the chosen transport, then group barrier ----
  if (lane < 16) {
    if (fast) { fstore(gbuf + pslot, SENT); fstore(gbuf + 512 + pslot, SENT); }
    else      { cstore(gbuf + pslot, SENT); cstore(gbuf + 512 + pslot, SENT); }
  }
  __builtin_amdgcn_s_waitcnt(0);
  __syncthreads();
  if (tid == 0) {
    __hip_atomic_fetch_add(&bar[512 + gid * 32], 1u,
                           __ATOMIC_RELAXED, __HIP_MEMORY_SCOPE_AGENT);
    for (;;) {
      if (__hip_atomic_load(&bar[512 + gid * 32],
                            __ATOMIC_RELAXED, __HIP_MEMORY_SCOPE_AGENT) >= 8u) break;
      __builtin_amdgcn_s_sleep(1);
    }
  }
  __syncthreads();

  // ================= scan =================
  float Creg[4] = {0.f, 0.f, 0.f, 0.f};
  f32x4 xgs[2][4];                           // xg (f32, bias-added) for 8 steps

  for (int t8 = 0; t8 < S_; t8 += 8) {
    // ---- xg block: XG[(t',b),(g,jj)] = x[B0+b][t8+t'] @ Wx, 8 steps at once.
    // A rows = t''*4+b (mt picks t' hi/lo); B streamed from Bws (L2-hot),
    // reused across the 8 steps -> latency amortized. ----
    {
      f32x4 accx[2][4];
      #pragma unroll
      for (int mt = 0; mt < 2; ++mt)
        #pragma unroll
        for (int g = 0; g < 4; ++g) accx[mt][g] = (f32x4){0.f, 0.f, 0.f, 0.f};
      #pragma unroll 4
      for (int ks = 0; ks < 16; ++ks) {
        short8 bx[4];
        #pragma unroll
        for (int g = 0; g < 4; ++g)
          bx[g] = *(const short8*)(Bws +
              ((size_t)(idx * 64 + g * 16 + l15) * KTOT + DH + ks * 32 + kq8));
        #pragma unroll
        for (int mt = 0; mt < 2; ++mt) {
          const float* xs = x + ((size_t)(B0 + (l15 & 3)) * S_ +
                                 (t8 + mt * 4 + (l15 >> 2))) * DIN + ks * 32 + kq8;
          float4 v0 = *(const float4*)xs;
          float4 v1 = *(const float4*)(xs + 4);
          short8 ax;
          ax[0] = (short)f2bf(v0.x); ax[1] = (short)f2bf(v0.y);
          ax[2] = (short)f2bf(v0.z); ax[3] = (short)f2bf(v0.w);
          ax[4] = (short)f2bf(v1.x); ax[5] = (short)f2bf(v1.y);
          ax[6] = (short)f2bf(v1.z); ax[7] = (short)f2bf(v1.w);
          #pragma unroll
          for (int g = 0; g < 4; ++g) accx[mt][g] = mfma16(ax, bx[g], accx[mt][g]);
        }
      }
      // pack: lane (t''=lane>>4, jj=l15) holds steps t8+mt*4+t'' for its hcol
      #pragma unroll
      for (int mt = 0; mt < 2; ++mt)
        #pragma unroll
        for (int b = 0; b < 4; ++b) {
          xgs[mt][b][0] = accx[mt][0][b] + pbi;
          xgs[mt][b][1] = accx[mt][1][b] + pbf;
          xgs[mt][b][2] = accx[mt][2][b] + pbo;
          xgs[mt][b][3] = accx[mt][3][b] + pbc;
        }
    }

    for (int tt = 0; tt < 8; ++tt) {
      const int t = t8 + tt;
      f32x4 acc[4] = {{0,0,0,0},{0,0,0,0},{0,0,0,0},{0,0,0,0}};
      u64 tmp[32];

      if (t > 0) {
        // ---- poll H_{t-1}: detect + load straight into MFMA A-fragments ----
        const u64* hr = gbuf + (((size_t)((t - 1) & 3)) << 9);
        unsigned pend = 0xFFFFFFFFu;
        if (fast) {
          #pragma unroll
          for (int i = 0; i < 32; ++i)
            tmp[i] = fload(hr + ((i >> 1) << 5) + kq8 + ((i & 1) << 2) + b4);
          __builtin_amdgcn_s_waitcnt(0);
          __builtin_amdgcn_sched_barrier(0);
          #pragma unroll
          for (int i = 0; i < 32; ++i) if (tmp[i] != SENT) pend &= ~(1u << i);
          while (pend) {
            #pragma unroll
            for (int i = 0; i < 32; ++i) if (pend & (1u << i))
              tmp[i] = fload(hr + ((i >> 1) << 5) + kq8 + ((i & 1) << 2) + b4);
            __builtin_amdgcn_s_waitcnt(0);
            __builtin_amdgcn_sched_barrier(0);
            #pragma unroll
            for (int i = 0; i < 32; ++i)
              if ((pend & (1u << i)) && tmp[i] != SENT) pend &= ~(1u << i);
          }
        } else {
          #pragma unroll
          for (int i = 0; i < 32; ++i)
            tmp[i] = cload(hr + ((i >> 1) << 5) + kq8 + ((i & 1) << 2) + b4);
          #pragma unroll
          for (int i = 0; i < 32; ++i) if (tmp[i] != SENT) pend &= ~(1u << i);
          while (pend) {
            #pragma unroll
            for (int i = 0; i < 32; ++i) if (pend & (1u << i))
              tmp[i] = cload(hr + ((i >> 1) << 5) + kq8 + ((i & 1) << 2) + b4);
            #pragma unroll
            for (int i = 0; i < 32; ++i)
              if ((pend & (1u << i)) && tmp[i] != SENT) pend &= ~(1u << i);
          }
        }
        // ---- H-part MFMA straight from polled registers ----
        #pragma unroll
        for (int ks = 0; ks < 16; ++ks) {
          union { u64 q[2]; short8 s; } cv;
          cv.q[0] = tmp[2 * ks]; cv.q[1] = tmp[2 * ks + 1];
          #pragma unroll
          for (int g = 0; g < 4; ++g) acc[g] = mfma16(cv.s, bfrag[ks][g], acc[g]);
        }
      }

      // ---- re-sentinel buf[(t+2)&3]: committed before my next publish via the
      // pre-publish waitcnt; consumers order through their polls (induction) ----
      if (lane < 16 && t + 2 < S_) {
        u64* sp = gbuf + (((size_t)((t + 2) & 3)) << 9) + pslot;
        if (fast) fstore(sp, SENT); else cstore(sp, SENT);
      }

      // ---- gates (all lanes; rows duplicate batches mod 4 -> uniform) ----
      const int hsrc = ((tt & 3) << 4) | l15;
      float Hrow[4];
      #pragma unroll
      for (int b = 0; b < 4; ++b) {
        f32x4 xv = (tt >> 2) ? xgs[1][b] : xgs[0][b];
        float g0 = xv[0], g1 = xv[1], g2 = xv[2], g3 = xv[3];
        float pi = acc[0][b] + __shfl(g0, hsrc);
        float pf = acc[1][b] + __shfl(g1, hsrc);
        float po = acc[2][b] + __shfl(g2, hsrc);
        float pc = acc[3][b] + __shfl(g3, hsrc);
        float I = sigmoid_f(pi), F = sigmoid_f(pf), O = sigmoid_f(po);
        float Cc = tanh_f(pc);
        Creg[b] = F * Creg[b] + I * Cc;
        Hrow[b] = O * tanh_f(Creg[b]);
      }

      // ---- pack publish quad via shuffles (lane l: batch b4, hcols lb..lb+3) ----
      unsigned Hb[4];
      #pragma unroll
      for (int b = 0; b < 4; ++b) Hb[b] = f2bf(Hrow[b]);
      const int lb = lane & ~3;
      u64 pb = 0;
      #pragma unroll
      for (int j = 0; j < 4; ++j) {
        unsigned s0 = __shfl(Hb[0], lb + j);
        unsigned s1 = __shfl(Hb[1], lb + j);
        unsigned s2 = __shfl(Hb[2], lb + j);
        unsigned s3 = __shfl(Hb[3], lb + j);
        unsigned sv = s0;
        sv = (b4 == 1) ? s1 : sv;
        sv = (b4 == 2) ? s2 : sv;
        sv = (b4 == 3) ? s3 : sv;
        pb |= (u64)(sv & 0xFFFFu) << (16 * j);
      }

      if (t + 1 < S_) {
        // drain re-sentinel + prior out-stores before publish (ordering chain)
        __builtin_amdgcn_s_waitcnt(0);
        if (lane < 16) {
          u64* pp = gbuf + (((size_t)(t & 3)) << 9) + pslot;
          if (fast) fstore(pp, pb); else cstore(pp, pb);
        }
      }

      if (lane < 16) {
        #pragma unroll
        for (int b = 0; b < 4; ++b)
          out[((size_t)(B0 + b) * S_ + t) * DH + hcol] = Hrow[b];
        if (t == S_ - 1) {
          #pragma unroll
          for (int b = 0; b < 4; ++b)
            out[(size_t)B_ * S_ * DH + (size_t)(B0 + b) * DH + hcol] = Hrow[b];
        }
      }
    }
  }
}

extern "C" void kernel_launch(void* const* d_in, const int* in_sizes, int n_in,
                              void* d_out, int out_size, void* d_ws, size_t ws_size,
                              hipStream_t stream) {
  const float* x   = (const float*)d_in[0];
  const float* Wxi = (const float*)d_in[1];
  const float* Whi = (const float*)d_in[2];
  const float* bi  = (const float*)d_in[3];
  const float* Wxf = (const float*)d_in[4];
  const float* Whf = (const float*)d_in[5];
  const float* bfv = (const float*)d_in[6];
  const float* Wxo = (const float*)d_in[7];
  const float* Who = (const float*)d_in[8];
  const float* bo  = (const float*)d_in[9];
  const float* Wxc = (const float*)d_in[10];
  const float* Whc = (const float*)d_in[11];
  const float* bc  = (const float*)d_in[12];
  float* out = (float*)d_out;

  // ws layout (4.26 MiB total — round-1-proven scale):
  //   Bws   @ 0            : 4 MiB
  //   hfast @ 4 MiB        : 128 KiB (8 groups x 4 bufs x 512 u64)
  //   hfb   @ 4 MiB+128 KiB: 128 KiB (fallback, disjoint)
  //   bar   @ 4 MiB+256 KiB: 4 KiB   (done | ok | bar2)
  char* base = (char*)d_ws;
  unsigned short* Bws  = (unsigned short*)base;
  u64*   hfast  = (u64*)(base + ((size_t)4 << 20));
  u64*   hfb    = (u64*)(base + ((size_t)4 << 20) + (128u << 10));
  unsigned* bar = (unsigned*)(base + ((size_t)4 << 20) + (256u << 10));

  k_prep<<<1024, TPB, 0, stream>>>(Whi, Whf, Who, Whc, Wxi, Wxf, Wxo, Wxc,
                                   Bws, hfast, bar);
  k_scan<<<NWG, TPB, 0, stream>>>(x, bi, bfv, bo, bc, Bws, hfast, hfb, bar, out);
}

// Round 5
// 8361.314 us; speedup vs baseline: 1.0063x; 1.0063x over previous
//
#include <hip/hip_runtime.h>
#include <math.h>

#define B_   32
#define S_   1024
#define DIN  512
#define DH   512
#define KTOT 1024          // DH (Wh part) + DIN (Wx part) in Bws
#define NWG  64
#define TPB  256
#define HSCAP 1024         // bounded handshake rounds

typedef short short8 __attribute__((ext_vector_type(8)));  // 8 bf16 (4 VGPRs)
typedef float f32x4  __attribute__((ext_vector_type(4)));
typedef unsigned long long u64;

#define SENT  0xFFFFFFFFFFFFFFFFULL  // 4x bf16 NaN; |H|<1 so never produced by f2bf
#define TESTV 0xFFFFFFFFFFFFFFFEULL  // handshake probe value (!= SENT, != poison)

__device__ __forceinline__ unsigned short f2bf(float f) {
  unsigned u = __float_as_uint(f);
  u += 0x7FFFu + ((u >> 16) & 1u);   // RNE
  return (unsigned short)(u >> 16);
}
__device__ __forceinline__ float sigmoid_f(float z) {
  return 1.f / (1.f + __expf(-z));
}
__device__ __forceinline__ float tanh_f(float z) {
  float e = __expf(-2.f * fabsf(z));
  float t = (1.f - e) / (1.f + e);
  return z < 0.f ? -t : t;
}
__device__ __forceinline__ f32x4 mfma16(short8 a, short8 b, f32x4 c) {
  return __builtin_amdgcn_mfma_f32_16x16x32_bf16(a, b, c, 0, 0, 0);
}
// proven LLC transport (rounds 0-1): agent-scope, sc0 sc1
__device__ __forceinline__ u64 cload(const u64* p) {
  return __hip_atomic_load(p, __ATOMIC_RELAXED, __HIP_MEMORY_SCOPE_AGENT);
}
__device__ __forceinline__ void cstore(u64* p, u64 v) {
  __hip_atomic_store(p, v, __ATOMIC_RELAXED, __HIP_MEMORY_SCOPE_AGENT);
}
// XCD-local transport. Store MUST be a plain write-back L2 store (NO volatile:
// LLVM lowers volatile stores with sc0 sc1 -> write-through to IC, which is
// exactly the round-4 regression). Plain store + compiler barrier keeps the
// line dirty in the XCD's L2; sc0 load bypasses L1 and reads that same L2.
__device__ __forceinline__ void fstore(u64* p, u64 v) {
  *p = v;
  asm volatile("" ::: "memory");   // no elimination/motion; store stays plain
}
__device__ __forceinline__ u64 fload(const u64* p) {
  u64 v;
  asm volatile("global_load_dwordx2 %0, %1, off sc0" : "=v"(v) : "v"(p) : "memory");
  return v;   // NOT valid until s_waitcnt; callers drain + sched_barrier before use
}

// B-operand layout: Bws[idx 0..31][c 0..63][k 0..1023], c = gate*16 + jj,
// hcol = idx*16 + jj, k<512 -> Wh, else Wx.
__global__ void k_prep(const float* __restrict__ Whi, const float* __restrict__ Whf,
                       const float* __restrict__ Who, const float* __restrict__ Whc,
                       const float* __restrict__ Wxi, const float* __restrict__ Wxf,
                       const float* __restrict__ Wxo, const float* __restrict__ Wxc,
                       unsigned short* __restrict__ Bws, u64* __restrict__ hfast,
                       unsigned* __restrict__ bar) {
  int chunk = blockIdx.x * TPB + threadIdx.x;      // 0..262143, 8 elems each
  int idx = chunk >> 13;
  int rem = chunk & 8191;
  int c   = rem >> 7;             // gate*16 + jj
  int k8  = (rem & 127) << 3;
  int g    = c >> 4;
  int hcol = (idx << 4) | (c & 15);
  const float* Wh = (g == 0) ? Whi : (g == 1) ? Whf : (g == 2) ? Who : Whc;
  const float* Wx = (g == 0) ? Wxi : (g == 1) ? Wxf : (g == 2) ? Wxo : Wxc;
  short8 sv;
  #pragma unroll
  for (int j = 0; j < 8; ++j) {
    int k = k8 + j;
    float f = (k < DH) ? Wh[(size_t)k * DH + hcol] : Wx[(size_t)(k - DH) * DH + hcol];
    sv[j] = (short)f2bf(f);
  }
  *(short8*)(Bws + (size_t)chunk * 8) = sv;
  if (blockIdx.x == 0) {
    // zero barrier region (done | ok | bar2 | spare = 1024 u32)
    #pragma unroll
    for (int r = 0; r < 4; ++r) bar[threadIdx.x + r * 256] = 0;
    // erase all groups' buf0 (handshake buffer) at IC level so stale TESTV from
    // a previous launch can never produce a false handshake pass
    #pragma unroll
    for (int j = 0; j < 16; ++j) {
      int u = threadIdx.x * 16 + j;            // 0..4095
      cstore(&hfast[(size_t)(u >> 9) * 2048 + (u & 511)], SENT);
    }
  }
}

// Persistent LSTM scan. 8 groups x 8 WGs x 4 batches; group gid = w&7 (co-XCD
// under round-robin dispatch, VERIFIED at runtime by a bounded handshake over
// the fast transport with consensus over proven agent atomics; any anomaly ->
// fallback to the proven LLC protocol in a disjoint region).
// Waves are autonomous: 16 hcols x 4 gates, full-K Wh resident (256 VGPR),
// H exchange lands directly in MFMA A-fragments, zero in-loop barriers.
// x-projections computed in-scan every 8 steps (MFMA, streamed Wx, f32 kept).
__launch_bounds__(TPB, 1)
__global__ void k_scan(const float* __restrict__ x,
                       const float* __restrict__ bi, const float* __restrict__ bfv,
                       const float* __restrict__ bo, const float* __restrict__ bc,
                       const unsigned short* __restrict__ Bws,
                       u64* __restrict__ hfast,    // 8 groups x 4 bufs x 512 u64
                       u64* __restrict__ hfb,      // fallback region, same shape
                       unsigned* __restrict__ bar, // done[8x32] | ok | bar2
                       float* __restrict__ out) {
  __shared__ int sh_bad;
  __shared__ int sh_fast;

  const int tid  = threadIdx.x;
  const int w    = blockIdx.x;
  const int lane = tid & 63;
  const int wv   = tid >> 6;
  const int l15  = lane & 15;
  const int kq8  = (lane >> 4) << 3;
  const int b4   = lane & 3;

  const int gid = w & 7;            // presumptive XCD (round-robin)
  const int mem = w >> 3;           // position within group -> hcol slice
  const int hbase = mem * 64 + wv * 16;
  const int idx   = mem * 4 + wv;   // Bws idx block for this wave's 16 hcols
  const int hcol  = hbase + l15;
  const int pslot = (hbase + (l15 & ~3)) | b4;   // own publish/sentinel slot
  const int B0    = gid * 4;        // first batch of this group

  const float pbi = bi[hcol], pbf = bfv[hcol], pbo = bo[hcol], pbc = bc[hcol];

  // ---- weights resident: full-K Wh fragments for 16 hcols x 4 gates ----
  short8 bfrag[16][4];
  #pragma unroll
  for (int ks = 0; ks < 16; ++ks)
    #pragma unroll
    for (int g = 0; g < 4; ++g)
      bfrag[ks][g] = *(const short8*)(Bws +
          ((size_t)(idx * 64 + g * 16 + l15) * KTOT + ks * 32 + kq8));

  // ================= transport handshake (bounded, consensus) =================
  u64* fs = hfast + (size_t)gid * 2048;      // group's fast region (buf0 = [0,512))
  if (lane < 16) fstore(fs + pslot, TESTV);
  __builtin_amdgcn_s_waitcnt(0);

  int miss0 = 1, miss1 = 1;                  // poll slots tid and tid+256
  for (int r = 0; r < HSCAP && (miss0 | miss1); ++r) {
    u64 a = 0, c = 0;
    if (miss0) a = fload(fs + tid);
    if (miss1) c = fload(fs + tid + 256);
    __builtin_amdgcn_s_waitcnt(0);
    __builtin_amdgcn_sched_barrier(0);
    if (miss0 && a == TESTV) miss0 = 0;
    if (miss1 && c == TESTV) miss1 = 0;
  }
  if (tid == 0) sh_bad = 0;
  __syncthreads();
  if (miss0 | miss1) atomicAdd(&sh_bad, 1);
  __syncthreads();
  const int myok = (sh_bad == 0);

  if (tid == 0) {
    if (myok)
      __hip_atomic_fetch_add(&bar[256 + gid * 32], 1u,
                             __ATOMIC_RELAXED, __HIP_MEMORY_SCOPE_AGENT);
    __builtin_amdgcn_s_waitcnt(0);           // ok-add committed before done-add
    __hip_atomic_fetch_add(&bar[gid * 32], 1u,
                           __ATOMIC_RELAXED, __HIP_MEMORY_SCOPE_AGENT);
    for (;;) {
      if (__hip_atomic_load(&bar[gid * 32],
                            __ATOMIC_RELAXED, __HIP_MEMORY_SCOPE_AGENT) >= 8u) break;
      __builtin_amdgcn_s_sleep(1);
    }
    sh_fast = (__hip_atomic_load(&bar[256 + gid * 32],
                                 __ATOMIC_RELAXED, __HIP_MEMORY_SCOPE_AGENT) == 8u);
  }
  __syncthreads();
  const int fast = sh_fast;
  u64* gbuf = (fast ? hfast : hfb) + (size_t)gid * 2048;

  // ---- pre-sentinel buf0,buf1 via the chosen transport, then group barrier ----
  if (lane < 16) {
    if (fast) { fstore(gbuf + pslot, SENT); fstore(gbuf + 512 + pslot, SENT); }
    else      { cstore(gbuf + pslot, SENT); cstore(gbuf + 512 + pslot, SENT); }
  }
  __builtin_amdgcn_s_waitcnt(0);
  __syncthreads();
  if (tid == 0) {
    __hip_atomic_fetch_add(&bar[512 + gid * 32], 1u,
                           __ATOMIC_RELAXED, __HIP_MEMORY_SCOPE_AGENT);
    for (;;) {
      if (__hip_atomic_load(&bar[512 + gid * 32],
                            __ATOMIC_RELAXED, __HIP_MEMORY_SCOPE_AGENT) >= 8u) break;
      __builtin_amdgcn_s_sleep(1);
    }
  }
  __syncthreads();

  // ================= scan =================
  float Creg[4] = {0.f, 0.f, 0.f, 0.f};
  f32x4 xgs[2][4];                           // xg (f32, bias-added) for 8 steps

  for (int t8 = 0; t8 < S_; t8 += 8) {
    // ---- xg block: XG[(t',b),(g,jj)] = x[B0+b][t8+t'] @ Wx, 8 steps at once.
    // A rows = t''*4+b (mt picks t' hi/lo); B streamed from Bws (L2-hot),
    // reused across the 8 steps -> latency amortized. ----
    {
      f32x4 accx[2][4];
      #pragma unroll
      for (int mt = 0; mt < 2; ++mt)
        #pragma unroll
        for (int g = 0; g < 4; ++g) accx[mt][g] = (f32x4){0.f, 0.f, 0.f, 0.f};
      #pragma unroll 4
      for (int ks = 0; ks < 16; ++ks) {
        short8 bx[4];
        #pragma unroll
        for (int g = 0; g < 4; ++g)
          bx[g] = *(const short8*)(Bws +
              ((size_t)(idx * 64 + g * 16 + l15) * KTOT + DH + ks * 32 + kq8));
        #pragma unroll
        for (int mt = 0; mt < 2; ++mt) {
          const float* xs = x + ((size_t)(B0 + (l15 & 3)) * S_ +
                                 (t8 + mt * 4 + (l15 >> 2))) * DIN + ks * 32 + kq8;
          float4 v0 = *(const float4*)xs;
          float4 v1 = *(const float4*)(xs + 4);
          short8 ax;
          ax[0] = (short)f2bf(v0.x); ax[1] = (short)f2bf(v0.y);
          ax[2] = (short)f2bf(v0.z); ax[3] = (short)f2bf(v0.w);
          ax[4] = (short)f2bf(v1.x); ax[5] = (short)f2bf(v1.y);
          ax[6] = (short)f2bf(v1.z); ax[7] = (short)f2bf(v1.w);
          #pragma unroll
          for (int g = 0; g < 4; ++g) accx[mt][g] = mfma16(ax, bx[g], accx[mt][g]);
        }
      }
      // pack: lane (t''=lane>>4, jj=l15) holds steps t8+mt*4+t'' for its hcol
      #pragma unroll
      for (int mt = 0; mt < 2; ++mt)
        #pragma unroll
        for (int b = 0; b < 4; ++b) {
          xgs[mt][b][0] = accx[mt][0][b] + pbi;
          xgs[mt][b][1] = accx[mt][1][b] + pbf;
          xgs[mt][b][2] = accx[mt][2][b] + pbo;
          xgs[mt][b][3] = accx[mt][3][b] + pbc;
        }
    }

    for (int tt = 0; tt < 8; ++tt) {
      const int t = t8 + tt;
      f32x4 acc[4] = {{0,0,0,0},{0,0,0,0},{0,0,0,0},{0,0,0,0}};
      u64 tmp[32];

      if (t > 0) {
        // ---- poll H_{t-1}: detect + load straight into MFMA A-fragments ----
        const u64* hr = gbuf + (((size_t)((t - 1) & 3)) << 9);
        unsigned pend = 0xFFFFFFFFu;
        if (fast) {
          #pragma unroll
          for (int i = 0; i < 32; ++i)
            tmp[i] = fload(hr + ((i >> 1) << 5) + kq8 + ((i & 1) << 2) + b4);
          __builtin_amdgcn_s_waitcnt(0);
          __builtin_amdgcn_sched_barrier(0);
          #pragma unroll
          for (int i = 0; i < 32; ++i) if (tmp[i] != SENT) pend &= ~(1u << i);
          while (pend) {
            #pragma unroll
            for (int i = 0; i < 32; ++i) if (pend & (1u << i))
              tmp[i] = fload(hr + ((i >> 1) << 5) + kq8 + ((i & 1) << 2) + b4);
            __builtin_amdgcn_s_waitcnt(0);
            __builtin_amdgcn_sched_barrier(0);
            #pragma unroll
            for (int i = 0; i < 32; ++i)
              if ((pend & (1u << i)) && tmp[i] != SENT) pend &= ~(1u << i);
          }
        } else {
          #pragma unroll
          for (int i = 0; i < 32; ++i)
            tmp[i] = cload(hr + ((i >> 1) << 5) + kq8 + ((i & 1) << 2) + b4);
          #pragma unroll
          for (int i = 0; i < 32; ++i) if (tmp[i] != SENT) pend &= ~(1u << i);
          while (pend) {
            #pragma unroll
            for (int i = 0; i < 32; ++i) if (pend & (1u << i))
              tmp[i] = cload(hr + ((i >> 1) << 5) + kq8 + ((i & 1) << 2) + b4);
            #pragma unroll
            for (int i = 0; i < 32; ++i)
              if ((pend & (1u << i)) && tmp[i] != SENT) pend &= ~(1u << i);
          }
        }
        // ---- H-part MFMA straight from polled registers ----
        #pragma unroll
        for (int ks = 0; ks < 16; ++ks) {
          union { u64 q[2]; short8 s; } cv;
          cv.q[0] = tmp[2 * ks]; cv.q[1] = tmp[2 * ks + 1];
          #pragma unroll
          for (int g = 0; g < 4; ++g) acc[g] = mfma16(cv.s, bfrag[ks][g], acc[g]);
        }
      }

      // ---- re-sentinel buf[(t+2)&3]: committed before my next publish via the
      // pre-publish waitcnt; consumers order through their polls (induction) ----
      if (lane < 16 && t + 2 < S_) {
        u64* sp = gbuf + (((size_t)((t + 2) & 3)) << 9) + pslot;
        if (fast) fstore(sp, SENT); else cstore(sp, SENT);
      }

      // ---- gates (all lanes; rows duplicate batches mod 4 -> uniform) ----
      const int hsrc = ((tt & 3) << 4) | l15;
      float Hrow[4];
      #pragma unroll
      for (int b = 0; b < 4; ++b) {
        f32x4 xv = (tt >> 2) ? xgs[1][b] : xgs[0][b];
        float g0 = xv[0], g1 = xv[1], g2 = xv[2], g3 = xv[3];
        float pi = acc[0][b] + __shfl(g0, hsrc);
        float pf = acc[1][b] + __shfl(g1, hsrc);
        float po = acc[2][b] + __shfl(g2, hsrc);
        float pc = acc[3][b] + __shfl(g3, hsrc);
        float I = sigmoid_f(pi), F = sigmoid_f(pf), O = sigmoid_f(po);
        float Cc = tanh_f(pc);
        Creg[b] = F * Creg[b] + I * Cc;
        Hrow[b] = O * tanh_f(Creg[b]);
      }

      // ---- pack publish quad via shuffles (lane l: batch b4, hcols lb..lb+3) ----
      unsigned Hb[4];
      #pragma unroll
      for (int b = 0; b < 4; ++b) Hb[b] = f2bf(Hrow[b]);
      const int lb = lane & ~3;
      u64 pb = 0;
      #pragma unroll
      for (int j = 0; j < 4; ++j) {
        unsigned s0 = __shfl(Hb[0], lb + j);
        unsigned s1 = __shfl(Hb[1], lb + j);
        unsigned s2 = __shfl(Hb[2], lb + j);
        unsigned s3 = __shfl(Hb[3], lb + j);
        unsigned sv = s0;
        sv = (b4 == 1) ? s1 : sv;
        sv = (b4 == 2) ? s2 : sv;
        sv = (b4 == 3) ? s3 : sv;
        pb |= (u64)(sv & 0xFFFFu) << (16 * j);
      }

      if (t + 1 < S_) {
        // drain re-sentinel + prior out-stores before publish (ordering chain)
        __builtin_amdgcn_s_waitcnt(0);
        if (lane < 16) {
          u64* pp = gbuf + (((size_t)(t & 3)) << 9) + pslot;
          if (fast) fstore(pp, pb); else cstore(pp, pb);
        }
      }

      if (lane < 16) {
        #pragma unroll
        for (int b = 0; b < 4; ++b)
          out[((size_t)(B0 + b) * S_ + t) * DH + hcol] = Hrow[b];
        if (t == S_ - 1) {
          #pragma unroll
          for (int b = 0; b < 4; ++b)
            out[(size_t)B_ * S_ * DH + (size_t)(B0 + b) * DH + hcol] = Hrow[b];
        }
      }
    }
  }
}

extern "C" void kernel_launch(void* const* d_in, const int* in_sizes, int n_in,
                              void* d_out, int out_size, void* d_ws, size_t ws_size,
                              hipStream_t stream) {
  const float* x   = (const float*)d_in[0];
  const float* Wxi = (const float*)d_in[1];
  const float* Whi = (const float*)d_in[2];
  const float* bi  = (const float*)d_in[3];
  const float* Wxf = (const float*)d_in[4];
  const float* Whf = (const float*)d_in[5];
  const float* bfv = (const float*)d_in[6];
  const float* Wxo = (const float*)d_in[7];
  const float* Who = (const float*)d_in[8];
  const float* bo  = (const float*)d_in[9];
  const float* Wxc = (const float*)d_in[10];
  const float* Whc = (const float*)d_in[11];
  const float* bc  = (const float*)d_in[12];
  float* out = (float*)d_out;

  // ws layout (4.26 MiB total — round-1-proven scale):
  //   Bws   @ 0            : 4 MiB
  //   hfast @ 4 MiB        : 128 KiB (8 groups x 4 bufs x 512 u64)
  //   hfb   @ 4 MiB+128 KiB: 128 KiB (fallback, disjoint)
  //   bar   @ 4 MiB+256 KiB: 4 KiB   (done | ok | bar2)
  char* base = (char*)d_ws;
  unsigned short* Bws  = (unsigned short*)base;
  u64*   hfast  = (u64*)(base + ((size_t)4 << 20));
  u64*   hfb    = (u64*)(base + ((size_t)4 << 20) + (128u << 10));
  unsigned* bar = (unsigned*)(base + ((size_t)4 << 20) + (256u << 10));

  k_prep<<<1024, TPB, 0, stream>>>(Whi, Whf, Who, Whc, Wxi, Wxf, Wxo, Wxc,
                                   Bws, hfast, bar);
  k_scan<<<NWG, TPB, 0, stream>>>(x, bi, bfv, bo, bc, Bws, hfast, hfb, bar, out);
}

// Round 6
// 4733.182 us; speedup vs baseline: 1.7777x; 1.7665x over previous
//
#include <hip/hip_runtime.h>
#include <math.h>

#define B_   32
#define S_   1024
#define DIN  512
#define DH   512
#define KTOT 1024          // DH (H part) + DIN (x part)
#define NWG  64
#define TPB  256
#define NB   4             // rotating H-exchange buffers
#define HB64 4096          // u64 per buffer: 2 groups x 2048
#define RPAD 17            // R row stride in floats: conflict-free scalar access

typedef short short8 __attribute__((ext_vector_type(8)));  // 8 bf16 (4 VGPRs)
typedef float f32x4  __attribute__((ext_vector_type(4)));
typedef unsigned long long u64;

#define SENT 0xFFFFFFFFFFFFFFFFULL   // 4x bf16 NaN; |H|<1 so never produced by f2bf

__device__ __forceinline__ unsigned short f2bf(float f) {
  unsigned u = __float_as_uint(f);
  u += 0x7FFFu + ((u >> 16) & 1u);   // RNE
  return (unsigned short)(u >> 16);
}

__device__ __forceinline__ float sigmoid_f(float z) {
  return 1.f / (1.f + __expf(-z));
}
__device__ __forceinline__ float tanh_f(float z) {
  float e = __expf(-2.f * fabsf(z));
  float t = (1.f - e) / (1.f + e);
  return z < 0.f ? -t : t;
}

__device__ __forceinline__ f32x4 mfma16(short8 a, short8 b, f32x4 c) {
  return __builtin_amdgcn_mfma_f32_16x16x32_bf16(a, b, c, 0, 0, 0);
}

__device__ __forceinline__ u64 cload(const u64* p) {
  return __hip_atomic_load(p, __ATOMIC_RELAXED, __HIP_MEMORY_SCOPE_AGENT);
}
__device__ __forceinline__ void cstore(u64* p, u64 v) {
  __hip_atomic_store(p, v, __ATOMIC_RELAXED, __HIP_MEMORY_SCOPE_AGENT);
}

// B-operand layout: Bws[idx 0..31][c 0..63][k 0..1023], c = gate*16 + jj,
// hcol = idx*16 + jj, k<512 -> Wh, else Wx. Shared by both batch groups.
__global__ void k_prep(const float* __restrict__ Whi, const float* __restrict__ Whf,
                       const float* __restrict__ Who, const float* __restrict__ Whc,
                       const float* __restrict__ Wxi, const float* __restrict__ Wxf,
                       const float* __restrict__ Wxo, const float* __restrict__ Wxc,
                       unsigned short* __restrict__ Bws, unsigned* __restrict__ bar) {
  int chunk = blockIdx.x * TPB + threadIdx.x;      // 0..262143, 8 elems each
  int idx = chunk >> 13;
  int rem = chunk & 8191;
  int c   = rem >> 7;             // gate*16 + jj
  int k8  = (rem & 127) << 3;
  int g    = c >> 4;
  int hcol = (idx << 4) | (c & 15);
  const float* Wh = (g == 0) ? Whi : (g == 1) ? Whf : (g == 2) ? Who : Whc;
  const float* Wx = (g == 0) ? Wxi : (g == 1) ? Wxf : (g == 2) ? Wxo : Wxc;
  short8 sv;
  #pragma unroll
  for (int j = 0; j < 8; ++j) {
    int k = k8 + j;
    float f = (k < DH) ? Wh[(size_t)k * DH + hcol] : Wx[(size_t)(k - DH) * DH + hcol];
    sv[j] = (short)f2bf(f);
  }
  *(short8*)(Bws + (size_t)chunk * 8) = sv;
  if (blockIdx.x == 0 && threadIdx.x < 256) bar[threadIdx.x] = 0;  // reset startup barrier
}

// Persistent fused LSTM scan (round-1 verified protocol). 2 independent
// batch-groups of 32 WGs (16 batches, M=16 MFMA). H exchange: fragment-direct
// LLC slots — each wave polls only its K-quarter (8 u64/thread, 8 producer
// WGs) straight into MFMA A-fragments. 4 rotating buffers.
// Round-6 edits: (1) R double-buffer -> SYNC B deleted (1 barrier/step);
// (2) first poll round issued in the previous step's tail (overlaps out-stores
// and x-part MFMA), detection at loop top only finishes/retries.
__launch_bounds__(TPB, 1)
__global__ void k_scan(const float* __restrict__ x,
                       const float* __restrict__ bi, const float* __restrict__ bfv,
                       const float* __restrict__ bo, const float* __restrict__ bc,
                       const unsigned short* __restrict__ Bws,
                       u64* __restrict__ hbuf64,   // NB buffers of [2 groups][2048] u64
                       unsigned* __restrict__ bar, // 8 startup counters, 128B apart
                       float* __restrict__ out) {
  __shared__ float R[2][4 * 64 * RPAD];      // double-buffered per-wave partials

  const int tid  = threadIdx.x;
  const int w    = blockIdx.x;
  const int lane = tid & 63;
  const int wv   = tid >> 6;                 // wave 0..3 = K-quarter owner
  const int g    = w >> 5;                   // batch group 0..1
  const int idx  = w & 31;                   // H-col block 0..31

  const int eb   = tid >> 4;                 // group-local batch row 0..15
  const int ej   = tid & 15;                 // local hcol 0..15
  const int hcol = (idx << 4) | ej;
  const int batch = (g << 4) | eb;

  const int r0 = lane & 15;
  const int kq = (lane >> 4) << 3;

  const float pbi = bi[hcol], pbf = bfv[hcol], pbo = bo[hcol], pbc = bc[hcol];
  float Creg = 0.f;

  // publisher slot for this thread's 4-col quad (only tid%4==0 stores)
  int ch   = (idx << 4) | (ej & ~3);         // quad base H-col 0..511
  int wvt  = ch >> 7;                        // consumer wave (K-quarter)
  int cq   = ch & 127;
  int ksq  = cq >> 5;
  int kqi  = (cq & 31) >> 3;
  int uh   = (cq >> 2) & 1;
  const int pslot = (g << 11) | (wvt << 9) | (((ksq << 1) | uh) << 6) | (kqi << 4) | eb;

  // consumer poll base: slot (g, wv, i, lane) holds H[lane&15][wv*128+ks*32+(lane>>4)*8+uh*4 ..+3]
  const int cbase = (g << 11) | (wv << 9) | lane;

  // weights -> registers for the whole scan (128 VGPRs)
  short8 bfrag[8][4];
  {
    const int col0 = lane & 15;
    #pragma unroll
    for (int ks = 0; ks < 8; ++ks) {
      int kb = (ks < 4) ? (wv * 128 + ks * 32 + kq)
                        : (DH + wv * 128 + (ks - 4) * 32 + kq);
      #pragma unroll
      for (int nf = 0; nf < 4; ++nf) {
        int col = nf * 16 + col0;
        bfrag[ks][nf] = *(const short8*)(Bws + ((size_t)((idx << 6) | col) * KTOT + kb));
      }
    }
  }

  // pre-sentinel buf0 & buf1 (first in-loop sentinel targets buf2), then
  // startup barrier: all sentinels at LLC before anyone can publish/poll
  // (also covers workspace 0xAA poison).
  if ((tid & 3) == 0) {
    cstore(&hbuf64[pslot], SENT);
    cstore(&hbuf64[HB64 + pslot], SENT);
  }
  __builtin_amdgcn_s_waitcnt(0);
  __syncthreads();
  if (tid == 0) {
    __hip_atomic_fetch_add(&bar[(w & 7) * 32], 1u,
                           __ATOMIC_RELAXED, __HIP_MEMORY_SCOPE_AGENT);
    for (;;) {
      unsigned s = 0;
      #pragma unroll
      for (int i = 0; i < 8; ++i)
        s += __hip_atomic_load(&bar[i * 32], __ATOMIC_RELAXED, __HIP_MEMORY_SCOPE_AGENT);
      if (s >= (unsigned)NWG) break;
      __builtin_amdgcn_s_sleep(1);
    }
  }
  __syncthreads();

  // x A-fragment base for this lane (row = g*16 + r0, K-quarter wv, sub-slice kq)
  const float* xlane = x + (size_t)((g << 4) | r0) * (S_ * DIN) + (wv * 128 + kq);

  f32x4 acc[4];
  // x-part for t=0, straight from global into fragments
  {
    #pragma unroll
    for (int nf = 0; nf < 4; ++nf) acc[nf] = (f32x4){0.f, 0.f, 0.f, 0.f};
    #pragma unroll
    for (int ksx = 0; ksx < 4; ++ksx) {
      float4 v0 = *(const float4*)(xlane + ksx * 32);
      float4 v1 = *(const float4*)(xlane + ksx * 32 + 4);
      short8 ax;
      ax[0] = (short)f2bf(v0.x); ax[1] = (short)f2bf(v0.y);
      ax[2] = (short)f2bf(v0.z); ax[3] = (short)f2bf(v0.w);
      ax[4] = (short)f2bf(v1.x); ax[5] = (short)f2bf(v1.y);
      ax[6] = (short)f2bf(v1.z); ax[7] = (short)f2bf(v1.w);
      #pragma unroll
      for (int nf = 0; nf < 4; ++nf) acc[nf] = mfma16(ax, bfrag[4 + ksx][nf], acc[nf]);
    }
  }

  u64 tmp[8];                // poll registers (first round issued in prior tail)
  unsigned pending = 0xFFu;

  for (int t = 0; t < S_; ++t) {
    if (t > 0) {
      // ---- finish detection of H_{t-1}: first round was issued in the
      // previous step's tail; check it, then retry only pending slots ----
      const u64* hr = hbuf64 + (size_t)((t - 1) & 3) * HB64;
      #pragma unroll
      for (int i = 0; i < 8; ++i) if (tmp[i] != SENT) pending &= ~(1u << i);
      while (pending) {
        #pragma unroll
        for (int i = 0; i < 8; ++i)
          if (pending & (1u << i)) tmp[i] = cload(&hr[cbase + (i << 6)]);
        #pragma unroll
        for (int i = 0; i < 8; ++i)
          if ((pending & (1u << i)) && tmp[i] != SENT) pending &= ~(1u << i);
      }
      // ---- H-part MFMA straight from polled registers ----
      #pragma unroll
      for (int ks = 0; ks < 4; ++ks) {
        union { u64 q[2]; short8 s; } cv;
        cv.q[0] = tmp[2 * ks]; cv.q[1] = tmp[2 * ks + 1];
        #pragma unroll
        for (int nf = 0; nf < 4; ++nf) acc[nf] = mfma16(cv.s, bfrag[ks][nf], acc[nf]);
      }
    }

    // partials to LDS (scalar stores, stride 17 -> conflict-free), buffer t&1
    {
      float* rp = &R[t & 1][tid * RPAD];
      #pragma unroll
      for (int nf = 0; nf < 4; ++nf) {
        #pragma unroll
        for (int m = 0; m < 4; ++m) rp[nf * 4 + m] = acc[nf][m];
      }
    }
    __syncthreads();   // SYNC A: all 4 quarters of H_{t-1} consumed, R complete

    // re-sentinel buf (t+2)%4: safe only post-SYNC-A (=> all 4 waves' polls
    // done => every group WG published H_{t-1} => finished reading that
    // buffer's H_{t-2}); drained by the publish waitcnt below.
    if (t + 2 < S_ && (tid & 3) == 0)
      cstore(&hbuf64[(size_t)((t + 2) & 3) * HB64 + pslot], SENT);

    // ---- cross-wave K reduction + gate math ----
    float pre0 = 0.f, pre1 = 0.f, pre2 = 0.f, pre3 = 0.f;
    {
      int ln = ((eb >> 2) << 4) | ej;
      int rg = eb & 3;
      #pragma unroll
      for (int v = 0; v < 4; ++v) {
        const float* q = &R[t & 1][(v * 64 + ln) * RPAD + rg];
        pre0 += q[0]; pre1 += q[4]; pre2 += q[8]; pre3 += q[12];
      }
    }
    float I  = sigmoid_f(pre0 + pbi);
    float F  = sigmoid_f(pre1 + pbf);
    float O  = sigmoid_f(pre2 + pbo);
    float Cc = tanh_f(pre3 + pbc);
    Creg = F * Creg + I * Cc;
    float H = O * tanh_f(Creg);

    // pack 4 neighboring lanes (same batch row, consecutive hcols) via shuffles
    unsigned hv = f2bf(H);
    int lb = lane & ~3;
    u64 p = (u64)__shfl(hv, lb) | ((u64)__shfl(hv, lb | 1) << 16)
          | ((u64)__shfl(hv, lb | 2) << 32) | ((u64)__shfl(hv, lb | 3) << 48);

    if (t + 1 < S_) {
      // waitcnt drains re-sentinel (issued above, partially acked during gate
      // math) + step-old out stores. Ensures sentinel-buf(t+2) at LLC before
      // data-buf(t) becomes visible (poison-safety chain).
      __builtin_amdgcn_s_waitcnt(0);
      if ((tid & 3) == 0)
        cstore(&hbuf64[(size_t)(t & 3) * HB64 + pslot], p);

      // ---- tail-issued first poll round for H_t (buf t&3): overlaps the
      // out-stores and the x-part MFMA below; detection finishes at t+1 top ----
      const u64* hrn = hbuf64 + (size_t)(t & 3) * HB64;
      pending = 0xFFu;
      #pragma unroll
      for (int i = 0; i < 8; ++i) tmp[i] = cload(&hrn[cbase + (i << 6)]);
    }

    // out-store AFTER publish: HBM write-ack never sits on the exchange path
    out[(size_t)batch * (S_ * DH) + (size_t)t * DH + hcol] = H;
    if (t == S_ - 1) out[(size_t)(B_ * S_ * DH) + (size_t)batch * DH + hcol] = H;  // Hf

    if (t + 1 < S_) {
      // ---- x-part for t+1 straight from global (L3-resident) into fragments;
      // overlaps other WGs' publish->visibility latency and our poll round ----
      #pragma unroll
      for (int nf = 0; nf < 4; ++nf) acc[nf] = (f32x4){0.f, 0.f, 0.f, 0.f};
      const float* xt = xlane + (size_t)(t + 1) * DIN;
      #pragma unroll
      for (int ksx = 0; ksx < 4; ++ksx) {
        float4 v0 = *(const float4*)(xt + ksx * 32);
        float4 v1 = *(const float4*)(xt + ksx * 32 + 4);
        short8 ax;
        ax[0] = (short)f2bf(v0.x); ax[1] = (short)f2bf(v0.y);
        ax[2] = (short)f2bf(v0.z); ax[3] = (short)f2bf(v0.w);
        ax[4] = (short)f2bf(v1.x); ax[5] = (short)f2bf(v1.y);
        ax[6] = (short)f2bf(v1.z); ax[7] = (short)f2bf(v1.w);
        #pragma unroll
        for (int nf = 0; nf < 4; ++nf) acc[nf] = mfma16(ax, bfrag[4 + ksx][nf], acc[nf]);
      }
    }
    // SYNC B deleted: R is double-buffered (WAR gone) and a wave cannot reach
    // step t+2's R-write without passing SYNC A(t+1), which waits for all
    // waves to finish their step-t R reads.
  }
}

extern "C" void kernel_launch(void* const* d_in, const int* in_sizes, int n_in,
                              void* d_out, int out_size, void* d_ws, size_t ws_size,
                              hipStream_t stream) {
  const float* x   = (const float*)d_in[0];
  const float* Wxi = (const float*)d_in[1];
  const float* Whi = (const float*)d_in[2];
  const float* bi  = (const float*)d_in[3];
  const float* Wxf = (const float*)d_in[4];
  const float* Whf = (const float*)d_in[5];
  const float* bfv = (const float*)d_in[6];
  const float* Wxo = (const float*)d_in[7];
  const float* Who = (const float*)d_in[8];
  const float* bo  = (const float*)d_in[9];
  const float* Wxc = (const float*)d_in[10];
  const float* Whc = (const float*)d_in[11];
  const float* bc  = (const float*)d_in[12];
  float* out = (float*)d_out;

  // ws layout: Bws 4 MiB | hbuf 128 KiB (4 buffers) | bar 1 KiB
  unsigned short* Bws  = (unsigned short*)d_ws;
  u64*            hbuf = (u64*)((char*)d_ws + (size_t)4 * 1024 * 1024);
  unsigned*       bar  = (unsigned*)((char*)d_ws + (size_t)4 * 1024 * 1024 + 128 * 1024);

  k_prep<<<1024, TPB, 0, stream>>>(Whi, Whf, Who, Whc, Wxi, Wxf, Wxo, Wxc, Bws, bar);
  k_scan<<<NWG, TPB, 0, stream>>>(x, bi, bfv, bo, bc, Bws, hbuf, bar, out);
}

// Round 7
// 3298.029 us; speedup vs baseline: 2.5513x; 1.4352x over previous
//
#include <hip/hip_runtime.h>
#include <math.h>

#define B_   32
#define S_   1024
#define DIN  512
#define DH   512
#define KTOT 1024          // DH (H part) + DIN (x part)
#define NWG  64
#define TPB  256
#define NB   4             // rotating H-exchange buffers
#define HB64 4096          // u64 per buffer: 2 groups x 2048
#define RPAD 17            // R row stride in floats: conflict-free scalar access

typedef short short8 __attribute__((ext_vector_type(8)));  // 8 bf16 (4 VGPRs)
typedef float f32x4  __attribute__((ext_vector_type(4)));
typedef int   i32x4  __attribute__((ext_vector_type(4)));
typedef unsigned long long u64;

#define SENT 0xFFFFFFFFFFFFFFFFULL   // 4x bf16 NaN; |H|<1 so never produced by f2bf

__device__ __forceinline__ unsigned short f2bf(float f) {
  unsigned u = __float_as_uint(f);
  u += 0x7FFFu + ((u >> 16) & 1u);   // RNE
  return (unsigned short)(u >> 16);
}

__device__ __forceinline__ float sigmoid_f(float z) {
  return 1.f / (1.f + __expf(-z));
}
__device__ __forceinline__ float tanh_f(float z) {
  float e = __expf(-2.f * fabsf(z));
  float t = (1.f - e) / (1.f + e);
  return z < 0.f ? -t : t;
}

__device__ __forceinline__ f32x4 mfma16(short8 a, short8 b, f32x4 c) {
  return __builtin_amdgcn_mfma_f32_16x16x32_bf16(a, b, c, 0, 0, 0);
}

__device__ __forceinline__ u64 cload(const u64* p) {
  return __hip_atomic_load(p, __ATOMIC_RELAXED, __HIP_MEMORY_SCOPE_AGENT);
}
__device__ __forceinline__ void cstore(u64* p, u64 v) {
  __hip_atomic_store(p, v, __ATOMIC_RELAXED, __HIP_MEMORY_SCOPE_AGENT);
}

// B-operand layout: Bws[idx 0..31][c 0..63][k 0..1023], c = gate*16 + jj,
// hcol = idx*16 + jj, k<512 -> Wh, else Wx. Shared by both batch groups.
__global__ void k_prep(const float* __restrict__ Whi, const float* __restrict__ Whf,
                       const float* __restrict__ Who, const float* __restrict__ Whc,
                       const float* __restrict__ Wxi, const float* __restrict__ Wxf,
                       const float* __restrict__ Wxo, const float* __restrict__ Wxc,
                       unsigned short* __restrict__ Bws, unsigned* __restrict__ bar) {
  int chunk = blockIdx.x * TPB + threadIdx.x;      // 0..262143, 8 elems each
  int idx = chunk >> 13;
  int rem = chunk & 8191;
  int c   = rem >> 7;             // gate*16 + jj
  int k8  = (rem & 127) << 3;
  int g    = c >> 4;
  int hcol = (idx << 4) | (c & 15);
  const float* Wh = (g == 0) ? Whi : (g == 1) ? Whf : (g == 2) ? Who : Whc;
  const float* Wx = (g == 0) ? Wxi : (g == 1) ? Wxf : (g == 2) ? Wxo : Wxc;
  short8 sv;
  #pragma unroll
  for (int j = 0; j < 8; ++j) {
    int k = k8 + j;
    float f = (k < DH) ? Wh[(size_t)k * DH + hcol] : Wx[(size_t)(k - DH) * DH + hcol];
    sv[j] = (short)f2bf(f);
  }
  *(short8*)(Bws + (size_t)chunk * 8) = sv;
  if (blockIdx.x == 0 && threadIdx.x < 256) bar[threadIdx.x] = 0;  // reset startup barrier
}

// Persistent fused LSTM scan (round-1 verified protocol; only the H-exchange
// SLOT LAYOUT changed). 2 independent batch-groups of 32 WGs. Slot layout v2:
// slot = g*2048 + batch*128 + hcol_quad  (hcol_quad = hcol>>2, 0..127), so a
// consumer lane's A-fragment pair (8 consecutive hcols of its batch row) is
// ONE aligned 16B dwordx4 poll, and a wave's poll round is 4 instructions x
// 16 contiguous-64B lines = 64 line-requests (vs 512 with the strided v1
// layout) -> 8x lower request pressure at the coherence point.
__launch_bounds__(TPB, 1)
__global__ void k_scan(const float* __restrict__ x,
                       const float* __restrict__ bi, const float* __restrict__ bfv,
                       const float* __restrict__ bo, const float* __restrict__ bc,
                       const unsigned short* __restrict__ Bws,
                       u64* __restrict__ hbuf64,   // NB buffers of [2 groups][2048] u64
                       unsigned* __restrict__ bar, // 8 startup counters, 128B apart
                       float* __restrict__ out) {
  __shared__ float R[4 * 64 * RPAD];         // per-wave partial accumulators

  const int tid  = threadIdx.x;
  const int w    = blockIdx.x;
  const int lane = tid & 63;
  const int wv   = tid >> 6;                 // wave 0..3 = K-quarter owner
  const int g    = w >> 5;                   // batch group 0..1
  const int idx  = w & 31;                   // H-col block 0..31

  const int eb   = tid >> 4;                 // group-local batch row 0..15
  const int ej   = tid & 15;                 // local hcol 0..15
  const int hcol = (idx << 4) | ej;
  const int batch = (g << 4) | eb;

  const int r0 = lane & 15;
  const int kg = lane >> 4;
  const int kq = kg << 3;

  const float pbi = bi[hcol], pbf = bfv[hcol], pbo = bo[hcol], pbc = bc[hcol];
  float Creg = 0.f;

  // publisher slot (v2): quad of 4 consecutive hcols of batch eb.
  // slot = g*2048 + eb*128 + (hcol>>2); only tid%4==0 stores.
  const int pslot = (g << 11) + eb * 128 + idx * 4 + (ej >> 2);

  // consumer poll base (v2): lane (r0,kg) of wave wv reads, per ks, the 16B at
  // u64 index r0*128 + wv*32 + ks*8 + kg*2  = H[r0][wv*128+ks*32+kg*8 .. +7]
  const int cbase = (g << 11) + r0 * 128 + wv * 32 + kg * 2;

  // weights -> registers for the whole scan (128 VGPRs)
  short8 bfrag[8][4];
  {
    const int col0 = lane & 15;
    #pragma unroll
    for (int ks = 0; ks < 8; ++ks) {
      int kb = (ks < 4) ? (wv * 128 + ks * 32 + kq)
                        : (DH + wv * 128 + (ks - 4) * 32 + kq);
      #pragma unroll
      for (int nf = 0; nf < 4; ++nf) {
        int col = nf * 16 + col0;
        bfrag[ks][nf] = *(const short8*)(Bws + ((size_t)((idx << 6) | col) * KTOT + kb));
      }
    }
  }

  // pre-sentinel buf0 & buf1 (first in-loop sentinel targets buf2), then
  // startup barrier: all sentinels at LLC before anyone can publish/poll
  // (also covers workspace 0xAA poison).
  if ((tid & 3) == 0) {
    cstore(&hbuf64[pslot], SENT);
    cstore(&hbuf64[HB64 + pslot], SENT);
  }
  __builtin_amdgcn_s_waitcnt(0);
  __syncthreads();
  if (tid == 0) {
    __hip_atomic_fetch_add(&bar[(w & 7) * 32], 1u,
                           __ATOMIC_RELAXED, __HIP_MEMORY_SCOPE_AGENT);
    for (;;) {
      unsigned s = 0;
      #pragma unroll
      for (int i = 0; i < 8; ++i)
        s += __hip_atomic_load(&bar[i * 32], __ATOMIC_RELAXED, __HIP_MEMORY_SCOPE_AGENT);
      if (s >= (unsigned)NWG) break;
      __builtin_amdgcn_s_sleep(1);
    }
  }
  __syncthreads();

  // x A-fragment base for this lane (row = g*16 + r0, K-quarter wv, sub-slice kq)
  const float* xlane = x + (size_t)((g << 4) | r0) * (S_ * DIN) + (wv * 128 + kq);

  f32x4 acc[4];
  // x-part for t=0, straight from global into fragments
  {
    #pragma unroll
    for (int nf = 0; nf < 4; ++nf) acc[nf] = (f32x4){0.f, 0.f, 0.f, 0.f};
    #pragma unroll
    for (int ksx = 0; ksx < 4; ++ksx) {
      float4 v0 = *(const float4*)(xlane + ksx * 32);
      float4 v1 = *(const float4*)(xlane + ksx * 32 + 4);
      short8 ax;
      ax[0] = (short)f2bf(v0.x); ax[1] = (short)f2bf(v0.y);
      ax[2] = (short)f2bf(v0.z); ax[3] = (short)f2bf(v0.w);
      ax[4] = (short)f2bf(v1.x); ax[5] = (short)f2bf(v1.y);
      ax[6] = (short)f2bf(v1.z); ax[7] = (short)f2bf(v1.w);
      #pragma unroll
      for (int nf = 0; nf < 4; ++nf) acc[nf] = mfma16(ax, bfrag[4 + ksx][nf], acc[nf]);
    }
  }

  for (int t = 0; t < S_; ++t) {
    if (t > 0) {
      // ---- poll H_{t-1}: 4 x 16B coherent dwordx4 per lane, detect + load
      // straight into MFMA A-fragments; retry per 16B unit; both u64 halves
      // sentinel-checked (they come from two producer threads) ----
      const u64* hb = hbuf64 + (size_t)((t - 1) & 3) * HB64 + cbase;
      union { i32x4 v; u64 q[2]; } tb[4];
      unsigned pend = 0xFu;
      #pragma unroll
      for (int ks = 0; ks < 4; ++ks)
        asm volatile("global_load_dwordx4 %0, %1, off sc0 sc1"
                     : "=v"(tb[ks].v) : "v"(hb + ks * 8) : "memory");
      asm volatile("s_waitcnt vmcnt(0)" ::: "memory");
      __builtin_amdgcn_sched_barrier(0);
      #pragma unroll
      for (int ks = 0; ks < 4; ++ks)
        if (tb[ks].q[0] != SENT && tb[ks].q[1] != SENT) pend &= ~(1u << ks);
      while (pend) {
        #pragma unroll
        for (int ks = 0; ks < 4; ++ks)
          if (pend & (1u << ks))
            asm volatile("global_load_dwordx4 %0, %1, off sc0 sc1"
                         : "=v"(tb[ks].v) : "v"(hb + ks * 8) : "memory");
        asm volatile("s_waitcnt vmcnt(0)" ::: "memory");
        __builtin_amdgcn_sched_barrier(0);
        #pragma unroll
        for (int ks = 0; ks < 4; ++ks)
          if ((pend & (1u << ks)) && tb[ks].q[0] != SENT && tb[ks].q[1] != SENT)
            pend &= ~(1u << ks);
      }
      // ---- H-part MFMA straight from polled registers ----
      #pragma unroll
      for (int ks = 0; ks < 4; ++ks) {
        union { u64 q[2]; short8 s; } cv;
        cv.q[0] = tb[ks].q[0]; cv.q[1] = tb[ks].q[1];
        #pragma unroll
        for (int nf = 0; nf < 4; ++nf) acc[nf] = mfma16(cv.s, bfrag[ks][nf], acc[nf]);
      }
    }

    // partials to LDS (scalar stores, stride 17 -> conflict-free)
    {
      float* rp = &R[tid * RPAD];
      #pragma unroll
      for (int nf = 0; nf < 4; ++nf) {
        #pragma unroll
        for (int m = 0; m < 4; ++m) rp[nf * 4 + m] = acc[nf][m];
      }
    }
    __syncthreads();   // SYNC A: all 4 quarters of H_{t-1} consumed, R complete

    // re-sentinel buf (t+2)%4: safe only post-SYNC-A (=> all 4 waves' polls
    // done => every group WG published H_{t-1} => finished reading that
    // buffer's H_{t-2}); drained by the publish waitcnt below.
    if (t + 2 < S_ && (tid & 3) == 0)
      cstore(&hbuf64[(size_t)((t + 2) & 3) * HB64 + pslot], SENT);

    // ---- cross-wave K reduction + gate math ----
    float pre0 = 0.f, pre1 = 0.f, pre2 = 0.f, pre3 = 0.f;
    {
      int ln = ((eb >> 2) << 4) | ej;
      int rg = eb & 3;
      #pragma unroll
      for (int v = 0; v < 4; ++v) {
        const float* q = &R[(v * 64 + ln) * RPAD + rg];
        pre0 += q[0]; pre1 += q[4]; pre2 += q[8]; pre3 += q[12];
      }
    }
    float I  = sigmoid_f(pre0 + pbi);
    float F  = sigmoid_f(pre1 + pbf);
    float O  = sigmoid_f(pre2 + pbo);
    float Cc = tanh_f(pre3 + pbc);
    Creg = F * Creg + I * Cc;
    float H = O * tanh_f(Creg);

    // pack 4 neighboring lanes (same batch row, consecutive hcols) via shuffles
    unsigned hv = f2bf(H);
    int lb = lane & ~3;
    u64 p = (u64)__shfl(hv, lb) | ((u64)__shfl(hv, lb | 1) << 16)
          | ((u64)__shfl(hv, lb | 2) << 32) | ((u64)__shfl(hv, lb | 3) << 48);

    if (t + 1 < S_) {
      // waitcnt drains only step-old stores (re-sentinel from above, out from
      // t-1): near-free. Ensures sentinel-buf(t+2) at LLC before data-buf(t)
      // becomes visible (poison-safety chain for the next buffer).
      __builtin_amdgcn_s_waitcnt(0);
      if ((tid & 3) == 0)
        cstore(&hbuf64[(size_t)(t & 3) * HB64 + pslot], p);
    }

    // out-store AFTER publish: HBM write-ack never sits on the exchange path
    out[(size_t)batch * (S_ * DH) + (size_t)t * DH + hcol] = H;
    if (t == S_ - 1) out[(size_t)(B_ * S_ * DH) + (size_t)batch * DH + hcol] = H;  // Hf

    if (t + 1 < S_) {
      // ---- x-part for t+1 straight from global (L3-resident) into fragments;
      // overlaps other WGs' publish->visibility latency ----
      #pragma unroll
      for (int nf = 0; nf < 4; ++nf) acc[nf] = (f32x4){0.f, 0.f, 0.f, 0.f};
      const float* xt = xlane + (size_t)(t + 1) * DIN;
      #pragma unroll
      for (int ksx = 0; ksx < 4; ++ksx) {
        float4 v0 = *(const float4*)(xt + ksx * 32);
        float4 v1 = *(const float4*)(xt + ksx * 32 + 4);
        short8 ax;
        ax[0] = (short)f2bf(v0.x); ax[1] = (short)f2bf(v0.y);
        ax[2] = (short)f2bf(v0.z); ax[3] = (short)f2bf(v0.w);
        ax[4] = (short)f2bf(v1.x); ax[5] = (short)f2bf(v1.y);
        ax[6] = (short)f2bf(v1.z); ax[7] = (short)f2bf(v1.w);
        #pragma unroll
        for (int nf = 0; nf < 4; ++nf) acc[nf] = mfma16(ax, bfrag[4 + ksx][nf], acc[nf]);
      }
    }
    __syncthreads();   // SYNC B: separates R reads (step t) from R writes (t+1)
  }
}

extern "C" void kernel_launch(void* const* d_in, const int* in_sizes, int n_in,
                              void* d_out, int out_size, void* d_ws, size_t ws_size,
                              hipStream_t stream) {
  const float* x   = (const float*)d_in[0];
  const float* Wxi = (const float*)d_in[1];
  const float* Whi = (const float*)d_in[2];
  const float* bi  = (const float*)d_in[3];
  const float* Wxf = (const float*)d_in[4];
  const float* Whf = (const float*)d_in[5];
  const float* bfv = (const float*)d_in[6];
  const float* Wxo = (const float*)d_in[7];
  const float* Who = (const float*)d_in[8];
  const float* bo  = (const float*)d_in[9];
  const float* Wxc = (const float*)d_in[10];
  const float* Whc = (const float*)d_in[11];
  const float* bc  = (const float*)d_in[12];
  float* out = (float*)d_out;

  // ws layout: Bws 4 MiB | hbuf 128 KiB (4 buffers) | bar 1 KiB
  unsigned short* Bws  = (unsigned short*)d_ws;
  u64*            hbuf = (u64*)((char*)d_ws + (size_t)4 * 1024 * 1024);
  unsigned*       bar  = (unsigned*)((char*)d_ws + (size_t)4 * 1024 * 1024 + 128 * 1024);

  k_prep<<<1024, TPB, 0, stream>>>(Whi, Whf, Who, Whc, Wxi, Wxf, Wxo, Wxc, Bws, bar);
  k_scan<<<NWG, TPB, 0, stream>>>(x, bi, bfv, bo, bc, Bws, hbuf, bar, out);
}